// Round 14
// baseline (59.406 us; speedup 1.0000x reference)
//
#include <hip/hip_runtime.h>
#include <stdint.h>

#define LMAX 8
#define KCH 32
#define NC  64
#define TT  2048
#define LN2D 0.6931471805599453
#define NEGE (-(1<<28))

struct __align__(16) PK { unsigned long long key; float logp; int len; };

__device__ __forceinline__ int fexp(float m) { return ((__float_as_int(m) >> 23) & 0xFF) - 127; }
__device__ __forceinline__ int fexpbits(float m) { return (__float_as_int(m) >> 23) & 0xFF; }
__device__ __forceinline__ float p2(int e) { return __int_as_float((e + 127) << 23); }
__device__ __forceinline__ float p2c(int e) { return (e < -126) ? 0.f : p2(e); }

// K1: pack pieces into 64-bit keys, pack sequence windows, zero M. (R7 verbatim)
__global__ void k_prep(const int* __restrict__ seq, const int* __restrict__ pieces,
                       const int* __restrict__ plens, const float* __restrict__ logp,
                       PK* __restrict__ pk, unsigned long long* __restrict__ w64,
                       float* __restrict__ M, int T, int V) {
  int idx = blockIdx.x * blockDim.x + threadIdx.x;
  if (idx < V) {
    const int* pr = pieces + idx * LMAX;
    int len = plens[idx];
    unsigned long long key = 0ull;
    #pragma unroll
    for (int l = 0; l < LMAX; ++l) {
      unsigned long long b = (unsigned long long)(pr[l] & 0xFF);
      if (l < len) key |= b << (8 * l);
    }
    PK o; o.key = key; o.logp = logp[idx]; o.len = len;
    pk[idx] = o;
  } else if (idx < V + T) {
    int t = idx - V;
    unsigned long long w = 0ull;
    #pragma unroll
    for (int l = 0; l < LMAX; ++l) {
      int pos = t + l;
      unsigned long long b = (pos < T) ? (unsigned long long)(seq[pos] & 0xFF) : 0xFFull;
      w |= b << (8 * l);
    }
    w64[t] = w;
  } else if (idx < V + T + T * LMAX) {
    M[idx - V - T] = 0.f;
  }
}

// K2: M[t][len-1] += p_v for every matching (t,v). (R7 verbatim)
__global__ void k_match(const PK* __restrict__ pk, const unsigned long long* __restrict__ w64,
                        float* __restrict__ M, int T, int V, int tPer) {
  int v = blockIdx.x * blockDim.x + threadIdx.x;
  PK p = pk[v];
  unsigned long long mask = (p.len >= 8) ? ~0ull : ((1ull << (8 * p.len)) - 1ull);
  unsigned long long key = p.key;
  int t0 = blockIdx.y * tPer;
  float prob = -1.f;
  for (int t = t0; t < t0 + tPer; ++t) {
    unsigned long long w = w64[t];
    if (((w ^ key) & mask) == 0ull) {
      if (prob < 0.f) prob = expf(p.logp);
      atomicAdd(&M[t * LMAX + (p.len - 1)], prob);
    }
  }
}

// K3a: chunk transfer-matrix columns. 16 blocks x 64 thr. Rolled quarter loop
// (compact code), batch-8 independent row loads per quarter.
__global__ __launch_bounds__(64, 1) void k_chunks(const float* __restrict__ M,
        float* __restrict__ Wt, int* __restrict__ EWc) {
  int gtid = blockIdx.x * 64 + threadIdx.x;    // 0..1023
  int task = gtid >> 3, b = gtid & 7;
  int dir = task >> 6, c = task & 63;
  int base = c * KCH;
  const float4* Mv = (const float4*)M;
  float v[8];
  #pragma unroll
  for (int i = 0; i < 8; ++i) v[i] = (i == b) ? 1.f : 0.f;
  int ec = 0;
  if (dir == 0) {          // alpha push-form
    #pragma unroll 1
    for (int q = 0; q < 4; ++q) {
      float4 buf[16];
      #pragma unroll
      for (int i = 0; i < 8; ++i) {
        int row = base + q * 8 + i;
        buf[2 * i]     = Mv[row * 2];
        buf[2 * i + 1] = Mv[row * 2 + 1];
      }
      #pragma unroll
      for (int i = 0; i < 8; ++i) {      // kk = q*8+i; (kk+j)&7 == (i+j)&7
        float4 c0 = buf[2 * i], c1 = buf[2 * i + 1];
        float a_ = v[i];
        v[(i + 1) & 7] = fmaf(a_, c0.x, v[(i + 1) & 7]);
        v[(i + 2) & 7] = fmaf(a_, c0.y, v[(i + 2) & 7]);
        v[(i + 3) & 7] = fmaf(a_, c0.z, v[(i + 3) & 7]);
        v[(i + 4) & 7] = fmaf(a_, c0.w, v[(i + 4) & 7]);
        v[(i + 5) & 7] = fmaf(a_, c1.x, v[(i + 5) & 7]);
        v[(i + 6) & 7] = fmaf(a_, c1.y, v[(i + 6) & 7]);
        v[(i + 7) & 7] = fmaf(a_, c1.z, v[(i + 7) & 7]);
        v[i]           = a_ * c1.w;
        if ((i & 3) == 3) {
          float mx = 0.f;
          #pragma unroll
          for (int q2 = 0; q2 < 8; ++q2) mx = fmaxf(mx, v[q2]);
          if (fexpbits(mx) != 0) {
            int e = fexp(mx); float sc = p2(-e);
            #pragma unroll
            for (int q2 = 0; q2 < 8; ++q2) v[q2] *= sc;
            ec += e;
          }
        }
      }
    }
  } else {                 // beta window-form
    #pragma unroll 1
    for (int q = 0; q < 4; ++q) {
      float4 buf[16];
      #pragma unroll
      for (int i = 0; i < 8; ++i) {
        int row = base + 31 - (q * 8 + i);
        buf[2 * i]     = Mv[row * 2];
        buf[2 * i + 1] = Mv[row * 2 + 1];
      }
      #pragma unroll
      for (int i = 0; i < 8; ++i) {      // (8-kk)&7 == (8-i)&7 etc.
        float4 c0 = buf[2 * i], c1 = buf[2 * i + 1];
        float nb =      c0.x * v[(8  - i) & 7];
        nb = fmaf(c0.y, v[(9  - i) & 7], nb);
        nb = fmaf(c0.z, v[(10 - i) & 7], nb);
        nb = fmaf(c0.w, v[(11 - i) & 7], nb);
        nb = fmaf(c1.x, v[(12 - i) & 7], nb);
        nb = fmaf(c1.y, v[(13 - i) & 7], nb);
        nb = fmaf(c1.z, v[(14 - i) & 7], nb);
        nb = fmaf(c1.w, v[(15 - i) & 7], nb);
        v[(7 - i) & 7] = nb;
        if ((i & 3) == 3) {
          float mx = 0.f;
          #pragma unroll
          for (int q2 = 0; q2 < 8; ++q2) mx = fmaxf(mx, v[q2]);
          if (fexpbits(mx) != 0) {
            int e = fexp(mx); float sc = p2(-e);
            #pragma unroll
            for (int q2 = 0; q2 < 8; ++q2) v[q2] *= sc;
            ec += e;
          }
        }
      }
    }
  }
  float mx = 0.f;
  #pragma unroll
  for (int i = 0; i < 8; ++i) mx = fmaxf(mx, v[i]);
  int ltask = dir * 64 + (dir ? 63 - c : c);
  float* wp = Wt + ltask * 64;
  if (fexpbits(mx) == 0) {
    #pragma unroll
    for (int i = 0; i < 8; ++i) wp[b * 8 + i] = 0.f;
    EWc[ltask * 8 + b] = NEGE;
  } else {
    int e = fexp(mx); float sc = p2(-e);
    #pragma unroll
    for (int i = 0; i < 8; ++i) wp[b * 8 + i] = v[i] * sc;
    EWc[ltask * 8 + b] = ec + e;
  }
}

// K3b: combine + fp64 replay + log. Rolled loops (compact code); level-A
// prefix columns stored into the just-consumed sWt slot (no Pm round-trip).
__global__ __launch_bounds__(128, 1) void k_fin(const float* __restrict__ M,
        const float* __restrict__ Wt, const int* __restrict__ EWc,
        float* __restrict__ aL, float* __restrict__ bL) {
  __shared__ float sWt[128][68];     // chunk matrices; after level A: prefix cols
  __shared__ int   sEW[128 * 8];
  __shared__ int   sEP[128 * 8];
  __shared__ float Gm[16 * 69];
  __shared__ float Sg[16 * 9];
  __shared__ int   EGs[16 * 8];
  __shared__ int   EsB[16];
  __shared__ float sCs[128 * 8];
  __shared__ int   sEacc[128];
  const int tid = threadIdx.x;
  const float4* Mv = (const float4*)M;

  #pragma unroll 1
  for (int i = tid; i < 128 * 16; i += 128) {
    int task = i >> 4, q = i & 15;
    float4 v4 = ((const float4*)Wt)[i];
    *(float4*)&sWt[task][q * 4] = v4;
  }
  #pragma unroll 1
  for (int i = tid; i < 1024; i += 128) sEW[i] = EWc[i];
  __syncthreads();

  // level A: basis through each group of 8 chunks; stash prefix col in sWt[lt]
  {
    const int dir = tid >> 6, w = (tid >> 3) & 7, b = tid & 7;
    float v[8];
    #pragma unroll
    for (int i = 0; i < 8; ++i) v[i] = (i == b) ? 1.f : 0.f;
    int ec = 0;
    #pragma unroll 1
    for (int c = 0; c < 8; ++c) {
      int lc = w * 8 + c, lt = dir * 64 + lc;
      sEP[lt * 8 + b] = ec;
      float* wp = &sWt[lt][0];
      int ew[8];
      #pragma unroll
      for (int j = 0; j < 8; ++j) ew[j] = sEW[lt * 8 + j];
      int emax = ew[0];
      #pragma unroll
      for (int j = 1; j < 8; ++j) emax = max(emax, ew[j]);
      float nv[8] = {0, 0, 0, 0, 0, 0, 0, 0};
      #pragma unroll
      for (int j = 0; j < 8; ++j) {
        float tj = v[j] * p2c(ew[j] - emax + 64);
        float4 ca = *(const float4*)(wp + j * 8);
        float4 cb = *(const float4*)(wp + j * 8 + 4);
        nv[0] = fmaf(tj, ca.x, nv[0]); nv[1] = fmaf(tj, ca.y, nv[1]);
        nv[2] = fmaf(tj, ca.z, nv[2]); nv[3] = fmaf(tj, ca.w, nv[3]);
        nv[4] = fmaf(tj, cb.x, nv[4]); nv[5] = fmaf(tj, cb.y, nv[5]);
        nv[6] = fmaf(tj, cb.z, nv[6]); nv[7] = fmaf(tj, cb.w, nv[7]);
      }
      // sWt[lt] fully consumed by this wave -> store prefix column (old v)
      #pragma unroll
      for (int i = 0; i < 8; ++i) wp[b * 8 + i] = v[i];
      float mx = 0.f;
      #pragma unroll
      for (int i = 0; i < 8; ++i) mx = fmaxf(mx, nv[i]);
      if (fexpbits(mx) == 0) {
        #pragma unroll
        for (int i = 0; i < 8; ++i) v[i] = 0.f;
        ec = NEGE;
      } else {
        int e = fexp(mx); float sc = p2(-e);
        #pragma unroll
        for (int i = 0; i < 8; ++i) v[i] = nv[i] * sc;
        ec = ec + emax + e - 64;
      }
    }
    float* gp = Gm + (dir * 8 + w) * 69 + b * 8;
    #pragma unroll
    for (int i = 0; i < 8; ++i) gp[i] = v[i];
    EGs[(dir * 8 + w) * 8 + b] = ec;
  }
  __syncthreads();

  // level B: sequential over 8 groups (8 lanes per dir)
  if (tid < 8 || (tid >= 64 && tid < 72)) {
    const int dir = (tid >= 64) ? 1 : 0, j = tid & 7;
    float s[8];
    #pragma unroll
    for (int i = 0; i < 8; ++i) s[i] = (i == 0) ? 1.f : 0.f;
    int Es = 0;
    #pragma unroll 1
    for (int w = 0; w < 8; ++w) {
      float sj = s[0];
      #pragma unroll
      for (int i = 1; i < 8; ++i) if (j == i) sj = s[i];
      Sg[(dir * 8 + w) * 9 + j] = sj;
      if (j == 0) EsB[dir * 8 + w] = Es;
      int eg[8];
      #pragma unroll
      for (int i = 0; i < 8; ++i) eg[i] = EGs[(dir * 8 + w) * 8 + i];
      int egmax = eg[0];
      #pragma unroll
      for (int i = 1; i < 8; ++i) egmax = max(egmax, eg[i]);
      int egj = eg[0];
      #pragma unroll
      for (int i = 1; i < 8; ++i) if (j == i) egj = eg[i];
      float tb = sj * p2c(egj - egmax + 64);
      const float* gp = Gm + (dir * 8 + w) * 69 + j * 8;
      float p[8];
      #pragma unroll
      for (int i = 0; i < 8; ++i) p[i] = gp[i] * tb;
      #pragma unroll
      for (int m = 1; m <= 4; m <<= 1)
        #pragma unroll
        for (int i = 0; i < 8; ++i) p[i] += __shfl_xor(p[i], m);
      float mx = 0.f;
      #pragma unroll
      for (int i = 0; i < 8; ++i) mx = fmaxf(mx, p[i]);
      int e = fexp(mx); float sc = p2(-e);
      #pragma unroll
      for (int i = 0; i < 8; ++i) s[i] = p[i] * sc;
      Es += egmax + e - 64;
    }
  }
  __syncthreads();

  // level C: chunk-start vectors from LDS-resident prefix columns
  {
    const int dir = tid >> 6, lc = tid & 63, w = lc >> 3;
    const int lt = dir * 64 + lc;
    float sg[8];
    #pragma unroll
    for (int b = 0; b < 8; ++b) sg[b] = Sg[(dir * 8 + w) * 9 + b];
    int Es = EsB[dir * 8 + w];
    int ep[8];
    #pragma unroll
    for (int b = 0; b < 8; ++b) ep[b] = sEP[lt * 8 + b];
    int epmax = ep[0];
    #pragma unroll
    for (int b = 1; b < 8; ++b) epmax = max(epmax, ep[b]);
    float cs[8] = {0, 0, 0, 0, 0, 0, 0, 0};
    #pragma unroll
    for (int b = 0; b < 8; ++b) {
      float coef = sg[b] * p2c(ep[b] - epmax + 64);
      const float* pp = &sWt[lt][b * 8];
      float4 ca = *(const float4*)pp;
      float4 cb = *(const float4*)(pp + 4);
      cs[0] = fmaf(coef, ca.x, cs[0]); cs[1] = fmaf(coef, ca.y, cs[1]);
      cs[2] = fmaf(coef, ca.z, cs[2]); cs[3] = fmaf(coef, ca.w, cs[3]);
      cs[4] = fmaf(coef, cb.x, cs[4]); cs[5] = fmaf(coef, cb.y, cs[5]);
      cs[6] = fmaf(coef, cb.z, cs[6]); cs[7] = fmaf(coef, cb.w, cs[7]);
    }
    float mx = 0.f;
    #pragma unroll
    for (int i = 0; i < 8; ++i) mx = fmaxf(mx, cs[i]);
    int phys = dir ? (63 - lc) : lc;
    float* cp = &sCs[(dir * 64 + phys) * 8];
    if (fexpbits(mx) == 0) {
      #pragma unroll
      for (int i = 0; i < 8; ++i) cp[i] = 0.f;
      sEacc[dir * 64 + phys] = NEGE;
    } else {
      int e = fexp(mx); float sc = p2(-e);
      #pragma unroll
      for (int i = 0; i < 8; ++i) cp[i] = cs[i] * sc;
      sEacc[dir * 64 + phys] = Es + epmax + e - 64;
    }
  }
  __syncthreads();

  // fp64 replay + log, rolled quarters with batch-8 register row loads
  {
    const int dir = tid >> 6;
    const int c = tid & 63;
    const int base = c * KCH;
    const float* cp = &sCs[(dir * 64 + c) * 8];
    double st[8];
    #pragma unroll
    for (int i = 0; i < 8; ++i) st[i] = (double)cp[i];
    const double eacc = (double)sEacc[dir * 64 + c];
    if (tid == 0) { aL[0] = 0.f; bL[TT] = 0.f; }
    if (dir == 0) {
      #pragma unroll 1
      for (int q = 0; q < 4; ++q) {
        float4 buf[16];
        #pragma unroll
        for (int i = 0; i < 8; ++i) {
          int row = base + q * 8 + i;
          buf[2 * i]     = Mv[row * 2];
          buf[2 * i + 1] = Mv[row * 2 + 1];
        }
        #pragma unroll
        for (int i = 0; i < 8; ++i) {    // kk = q*8+i; ring idx == (i+j)&7
          float4 c0 = buf[2 * i], c1 = buf[2 * i + 1];
          double a_ = st[i];
          st[(i + 1) & 7] = fma(a_, (double)c0.x, st[(i + 1) & 7]);
          st[(i + 2) & 7] = fma(a_, (double)c0.y, st[(i + 2) & 7]);
          st[(i + 3) & 7] = fma(a_, (double)c0.z, st[(i + 3) & 7]);
          st[(i + 4) & 7] = fma(a_, (double)c0.w, st[(i + 4) & 7]);
          st[(i + 5) & 7] = fma(a_, (double)c1.x, st[(i + 5) & 7]);
          st[(i + 6) & 7] = fma(a_, (double)c1.y, st[(i + 6) & 7]);
          st[(i + 7) & 7] = fma(a_, (double)c1.z, st[(i + 7) & 7]);
          st[i]           = a_ * (double)c1.w;
          double val = st[(i + 1) & 7];
          long long bits = __double_as_longlong(val);
          int e2 = (int)((bits >> 52) & 0x7ff) - 1023;
          double mant = __longlong_as_double((bits & 0xFFFFFFFFFFFFFLL) | 0x3FF0000000000000LL);
          float lg = log2f((float)mant);
          aL[base + q * 8 + i + 1] = (float)(((double)e2 + eacc + (double)lg) * LN2D);
        }
      }
    } else {
      #pragma unroll 1
      for (int q = 0; q < 4; ++q) {
        float4 buf[16];
        #pragma unroll
        for (int i = 0; i < 8; ++i) {
          int row = base + 31 - (q * 8 + i);
          buf[2 * i]     = Mv[row * 2];
          buf[2 * i + 1] = Mv[row * 2 + 1];
        }
        #pragma unroll
        for (int i = 0; i < 8; ++i) {
          float4 c0 = buf[2 * i], c1 = buf[2 * i + 1];
          double nb =            (double)c0.x * st[(8  - i) & 7];
          nb = fma((double)c0.y, st[(9  - i) & 7], nb);
          nb = fma((double)c0.z, st[(10 - i) & 7], nb);
          nb = fma((double)c0.w, st[(11 - i) & 7], nb);
          nb = fma((double)c1.x, st[(12 - i) & 7], nb);
          nb = fma((double)c1.y, st[(13 - i) & 7], nb);
          nb = fma((double)c1.z, st[(14 - i) & 7], nb);
          nb = fma((double)c1.w, st[(15 - i) & 7], nb);
          st[(7 - i) & 7] = nb;
          long long bits = __double_as_longlong(nb);
          int e2 = (int)((bits >> 52) & 0x7ff) - 1023;
          double mant = __longlong_as_double((bits & 0xFFFFFFFFFFFFFLL) | 0x3FF0000000000000LL);
          float lg = log2f((float)mant);
          bL[base + 31 - (q * 8 + i)] = (float)(((double)e2 + eacc + (double)lg) * LN2D);
        }
      }
    }
  }
}

// K4: dense output. (R7 verbatim)
__global__ void k_out(const PK* __restrict__ pk, const unsigned long long* __restrict__ w64,
                      const float* __restrict__ aL, const float* __restrict__ bL,
                      float* __restrict__ out, int T, int V, int tPer) {
  int v = blockIdx.x * blockDim.x + threadIdx.x;
  PK p = pk[v];
  unsigned long long mask = (p.len >= 8) ? ~0ull : ((1ull << (8 * p.len)) - 1ull);
  unsigned long long key = p.key;
  float norm = aL[T];
  float base = p.logp - norm;
  int t0 = blockIdx.y * tPer;
  for (int t = t0; t < t0 + tPer; ++t) {
    unsigned long long w = w64[t];
    float val = 0.f;
    if (((w ^ key) & mask) == 0ull)
      val = __expf(aL[t] + base + bL[t + p.len]);
    out[(size_t)t * V + v] = val;
  }
}

extern "C" void kernel_launch(void* const* d_in, const int* in_sizes, int n_in,
                              void* d_out, int out_size, void* d_ws, size_t ws_size,
                              hipStream_t stream) {
  const int* seq    = (const int*)d_in[0];
  const int* pieces = (const int*)d_in[1];
  const int* plens  = (const int*)d_in[2];
  const float* logp = (const float*)d_in[3];
  float* out = (float*)d_out;
  const int T = in_sizes[0];
  const int V = in_sizes[2];

  char* p = (char*)d_ws;
  PK* pk = (PK*)p;                                   p += (size_t)V * sizeof(PK);
  unsigned long long* w64 = (unsigned long long*)p;  p += (size_t)T * 8;
  float* M = (float*)p;                              p += (size_t)T * LMAX * 4;
  float* Wt = (float*)p;                             p += (size_t)128 * 64 * 4;
  int* EWc = (int*)p;                                p += (size_t)128 * 8 * 4;
  float* aL = (float*)p;                             p += 8208;
  float* bL = (float*)p;                             p += 8208;

  int prepN = V + T + T * LMAX;
  k_prep<<<(prepN + 255) / 256, 256, 0, stream>>>(seq, pieces, plens, logp, pk, w64, M, T, V);

  const int tPer2 = 128;
  dim3 g2(V / 256, T / tPer2);
  k_match<<<g2, 256, 0, stream>>>(pk, w64, M, T, V, tPer2);

  k_chunks<<<16, 64, 0, stream>>>(M, Wt, EWc);
  k_fin<<<1, 128, 0, stream>>>(M, Wt, EWc, aL, bL);

  const int tPer5 = 32;
  dim3 g5(V / 256, T / tPer5);
  k_out<<<g5, 256, 0, stream>>>(pk, w64, aL, bL, out, T, V, tPer5);
}